// Round 2
// baseline (181.850 us; speedup 1.0000x reference)
//
#include <hip/hip_runtime.h>
#include <hip/hip_bf16.h>

typedef __bf16 bf16x8 __attribute__((ext_vector_type(8)));
typedef float floatx4 __attribute__((ext_vector_type(4)));
typedef unsigned short u16;

#define HW 196    // 14*14
#define KP2 232   // LDS/global row stride (elements); 464 B = 29*16 -> conflict-free b128
#define CL 432    // ext copy length (elements)
#define NB 8
#define NC 128

// ---- Stage 1: 1x1 conv + ReLU + 3x3 Gaussian blur + bf16 cast; writes xf (normal)
// and xfr (K-reversed, zero-padded to KP2) ----
// grid (32, 8): o-group of 4 x batch. 512 threads: (half of K) x (pixel).
__global__ __launch_bounds__(512) void k_stage1(const float* __restrict__ x,
                                                const float* __restrict__ wc,
                                                __hip_bfloat16* __restrict__ xf,
                                                __hip_bfloat16* __restrict__ xfr) {
  const int og  = blockIdx.x;       // 0..31
  const int b   = blockIdx.y;       // 0..7
  const int t   = threadIdx.x;      // 0..511
  const int pix = t & 255;
  const int half = t >> 8;
  const float* xb = x + ((size_t)(b * 512 + half * 256)) * 256 + pix;
  const float* w0 = wc + og * 4 * 512 + half * 256;

  float a0 = 0.f, a1 = 0.f, a2 = 0.f, a3 = 0.f;
#pragma unroll 16
  for (int i = 0; i < 256; ++i) {
    float xv = xb[(size_t)i * 256];
    a0 = fmaf(xv, w0[i], a0);
    a1 = fmaf(xv, w0[512 + i], a1);
    a2 = fmaf(xv, w0[1024 + i], a2);
    a3 = fmaf(xv, w0[1536 + i], a3);
  }

  __shared__ float ybuf[4][512];
  ybuf[0][t] = a0; ybuf[1][t] = a1; ybuf[2][t] = a2; ybuf[3][t] = a3;
  __syncthreads();

  if (t < 256) {
#pragma unroll
    for (int oo = 0; oo < 4; ++oo)
      ybuf[oo][t] = fmaxf(ybuf[oo][t] + ybuf[oo][256 + t], 0.f);  // own slot only
  }
  __syncthreads();

  const float GC = 0.63661977236758138f;
  const float GE = GC * 0.13533528323661270f;
  const float GD = GC * 0.018315638888734179f;

  if (t < KP2) {
    int h = 0, w2 = 0;
    if (t < HW) { h = t / 14; w2 = t - h * 14; }
#pragma unroll
    for (int oo = 0; oo < 4; ++oo) {
      float v = 0.f;
      if (t < HW) {
        const float* yb = &ybuf[oo][h * 16 + w2];
        v = GD * (yb[0] + yb[2] + yb[32] + yb[34])
          + GE * (yb[1] + yb[16] + yb[18] + yb[33])
          + GC * yb[17];
      }
      const int row = b * NC + og * 4 + oo;
      __hip_bfloat16 bv = __float2bfloat16(v);
      xf[row * KP2 + t] = bv;
      const int ir = (t < HW) ? ((t == 0) ? 0 : (HW - t)) : t;   // reversed index
      xfr[row * KP2 + ir] = bv;
    }
  }
}

// ---- Stage 2: circular correlation via MFMA; plain stores of per-(c) partial max ----
// grid (64, 8) = (c-pair, b); 256 threads = 4 waves.
// R[a,c,p] = sum_{i'} Arev[a,i'] * row_c[(p+i') mod 196]
// MFMA 16x16x32 bf16: A[m=lane&15][k=quad*8+j], B[k][n=lane&15], D[m=quad*4+reg][n]
__global__ __launch_bounds__(256, 2) void k_cooc(const __hip_bfloat16* __restrict__ xf,
                                                 const __hip_bfloat16* __restrict__ xfr,
                                                 float* __restrict__ W) {
  const int cpair = blockIdx.x;   // 0..63
  const int b     = blockIdx.y;
  const int t     = threadIdx.x;

  __shared__ __align__(16) u16 Abuf[NC * KP2];     // 59392 B
  __shared__ __align__(16) u16 ext[2 * 8 * CL];    // 13824 B

  { // stage reversed-A rows (all 128 rows of batch b), flat b128 copy
    const uint4* src = (const uint4*)(xfr + (size_t)b * NC * KP2);
    uint4* dst = (uint4*)Abuf;
    for (int j = t; j < NC * KP2 / 8; j += 256) dst[j] = src[j];
  }
  { // 8 shift-copies of each of the 2 ext rows: ext[c2][S][m] = row[(m+S) mod 196]
    const u16* xfu = (const u16*)xf;
    for (int j = t; j < 2 * 8 * CL; j += 256) {
      const int c2 = j / (8 * CL);
      const int rem = j - c2 * 8 * CL;
      const int S = rem / CL;
      const int m = rem - S * CL;
      int idx = m + S;
      if (idx >= 2 * HW) idx -= 2 * HW; else if (idx >= HW) idx -= HW;
      ext[j] = xfu[(b * NC + cpair * 2 + c2) * KP2 + idx];
    }
  }
  __syncthreads();

  const int lane = t & 63;
  const int wv   = t >> 6;        // p-tiles {wv, wv+4, wv+8} (+12 for wave 0)
  const int n    = lane & 15;
  const int quad = lane >> 4;
  const int S    = n & 7;
  const int extoff = S * CL + (n & 8) + quad * 8;   // + p0 + i0 at use site
  const int arow   = n * KP2 + quad * 8;

  for (int c2 = 0; c2 < 2; ++c2) {
    const u16* eb = ext + c2 * 8 * CL;
    floatx4 acc[8][4];
#pragma unroll
    for (int at = 0; at < 8; ++at)
#pragma unroll
      for (int j = 0; j < 4; ++j) acc[at][j] = (floatx4){0.f, 0.f, 0.f, 0.f};

    for (int kb = 0; kb < 7; ++kb) {
      const int i0 = kb * 32;
      bf16x8 af[8];
#pragma unroll
      for (int at = 0; at < 8; ++at)
        af[at] = *((const bf16x8*)&Abuf[(at * 16) * KP2 + arow + i0]);

#define DO_PT(JC)                                                                \
      {                                                                          \
        const int p0 = (wv + 4 * (JC)) * 16;                                     \
        const bf16x8 bv = *((const bf16x8*)&eb[extoff + p0 + i0]);               \
        _Pragma("unroll")                                                        \
        for (int at = 0; at < 8; ++at)                                           \
          acc[at][JC] = __builtin_amdgcn_mfma_f32_16x16x32_bf16(af[at], bv,      \
                                                                acc[at][JC], 0, 0, 0); \
      }
      DO_PT(0)
      DO_PT(1)
      DO_PT(2)
      if (wv == 0) { DO_PT(3) }
#undef DO_PT
    }

    // epilogue: in-register 4:1 a-fold, plain stores to W[b][c][a1][p]
    const int c = cpair * 2 + c2;
    float* Wbc = W + ((size_t)(b * NC + c)) * 32 * HW;
#define EPI(JC)                                                                  \
    {                                                                            \
      const int p = (wv + 4 * (JC)) * 16 + n;                                    \
      if (p < HW) {                                                              \
        _Pragma("unroll")                                                        \
        for (int a0t = 0; a0t < 2; ++a0t) {                                      \
          _Pragma("unroll")                                                      \
          for (int rr = 0; rr < 4; ++rr) {                                       \
            float v = fmaxf(fmaxf(acc[a0t][JC][rr], acc[a0t + 2][JC][rr]),       \
                            fmaxf(acc[a0t + 4][JC][rr], acc[a0t + 6][JC][rr]));  \
            const int a1 = a0t * 16 + quad * 4 + rr;                             \
            Wbc[a1 * HW + p] = v;                                                \
          }                                                                      \
        }                                                                        \
      }                                                                          \
    }
    EPI(0)
    EPI(1)
    EPI(2)
    if (wv == 0) { EPI(3) }
#undef EPI
  }
}

// ---- Stage 3: per-slot max over the 49 contributors + sqrt + per-batch sum ----
__global__ __launch_bounds__(256) void k_max(const float* __restrict__ W,
                                             float* __restrict__ out,
                                             float* __restrict__ sums) {
  const int gid = blockIdx.x * 256 + threadIdx.x;   // 0..131071
  const int b = gid >> 14;
  const int r = gid & 16383;
  const float* Wb = W + (size_t)b * NC * 32 * HW;

  float m = 0.f;
#pragma unroll 8
  for (int a1 = 0; a1 < 32; ++a1) {
    const int s = (r - ((a1 * 8704) & 16383)) & 16383;   // c*196+p == s (mod 16384)
    {
      const unsigned c = ((unsigned)s * 85599u) >> 24;   // s / 196
      const int p = s - (int)c * HW;
      m = fmaxf(m, Wb[(int)c * (32 * HW) + a1 * HW + p]);
    }
    const int t2 = s + 16384;
    if (t2 < NC * HW) {
      const unsigned c = ((unsigned)t2 * 85599u) >> 24;
      const int p = t2 - (int)c * HW;
      m = fmaxf(m, Wb[(int)c * (32 * HW) + a1 * HW + p]);
    }
  }
  out[gid] = sqrtf(m);

  // per-batch sum of c_ij^2 = sum of m  (block spans a single b: 64 blocks / batch)
  float s = m;
#pragma unroll
  for (int off = 32; off > 0; off >>= 1) s += __shfl_down(s, off, 64);
  __shared__ float part[4];
  if ((threadIdx.x & 63) == 0) part[threadIdx.x >> 6] = s;
  __syncthreads();
  if (threadIdx.x == 0)
    atomicAdd(&sums[b], part[0] + part[1] + part[2] + part[3]);
}

// ---- Stage 4: normalize ----
__global__ __launch_bounds__(256) void k_norm(const float* __restrict__ sums,
                                              float* __restrict__ out) {
  const int gid = blockIdx.x * 256 + threadIdx.x;
  const int b = gid >> 14;
  out[gid] = out[gid] / (sums[b] + 1e-11f);
}

extern "C" void kernel_launch(void* const* d_in, const int* in_sizes, int n_in,
                              void* d_out, int out_size, void* d_ws, size_t ws_size,
                              hipStream_t stream) {
  const float* x  = (const float*)d_in[0];   // (8,512,16,16) fp32
  const float* wc = (const float*)d_in[1];   // (128,512) fp32

  char* ws = (char*)d_ws;
  __hip_bfloat16* xf  = (__hip_bfloat16*)ws;                       // 475136 B
  __hip_bfloat16* xfr = (__hip_bfloat16*)(ws + 475136);            // 475136 B
  float* W    = (float*)(ws + 950272);                             // 25690112 B
  float* sums = (float*)(ws + 950272 + 25690112);                  // 32 B

  hipMemsetAsync(sums, 0, NB * sizeof(float), stream);
  k_stage1<<<dim3(32, NB), 512, 0, stream>>>(x, wc, xf, xfr);
  k_cooc<<<dim3(64, NB), 256, 0, stream>>>(xf, xfr, W);
  k_max<<<(NB * 16384) / 256, 256, 0, stream>>>(W, (float*)d_out, sums);
  k_norm<<<(NB * 16384) / 256, 256, 0, stream>>>(sums, (float*)d_out);
}

// Round 3
// 118.743 us; speedup vs baseline: 1.5315x; 1.5315x over previous
//
#include <hip/hip_runtime.h>
#include <hip/hip_bf16.h>

typedef __bf16 bf16x8 __attribute__((ext_vector_type(8)));
typedef float floatx4 __attribute__((ext_vector_type(4)));
typedef unsigned short u16;
typedef unsigned int u32;

#define HW 196    // 14*14
#define KP2 232   // row stride (elements); 29 dwords%32=20 -> 2-way-max b128 reads
#define CL 432    // ext copy length (elements)
#define NB 8
#define NC 128
#define WROW 12544  // u32 per (b,a1) row of W  (= 25088 bf16 = 128c * 196p)

// ---- Stage 1: 1x1 conv + ReLU + 3x3 Gaussian blur + bf16 cast ----
// grid (8, 32) = (b, o-group of 4): flat_id%8==b -> per-XCD x[b] L2 residency.
__global__ __launch_bounds__(512) void k_stage1(const float* __restrict__ x,
                                                const float* __restrict__ wc,
                                                __hip_bfloat16* __restrict__ xf,
                                                __hip_bfloat16* __restrict__ xfr) {
  const int b   = blockIdx.x;       // 0..7
  const int og  = blockIdx.y;       // 0..31
  const int t   = threadIdx.x;      // 0..511
  const int pix = t & 255;
  const int half = t >> 8;
  const float* xb = x + ((size_t)(b * 512 + half * 256)) * 256 + pix;
  const float* w0 = wc + og * 4 * 512 + half * 256;

  float a0 = 0.f, a1 = 0.f, a2 = 0.f, a3 = 0.f;
#pragma unroll 16
  for (int i = 0; i < 256; ++i) {
    float xv = xb[(size_t)i * 256];
    a0 = fmaf(xv, w0[i], a0);
    a1 = fmaf(xv, w0[512 + i], a1);
    a2 = fmaf(xv, w0[1024 + i], a2);
    a3 = fmaf(xv, w0[1536 + i], a3);
  }

  __shared__ float ybuf[4][512];
  ybuf[0][t] = a0; ybuf[1][t] = a1; ybuf[2][t] = a2; ybuf[3][t] = a3;
  __syncthreads();

  if (t < 256) {
#pragma unroll
    for (int oo = 0; oo < 4; ++oo)
      ybuf[oo][t] = fmaxf(ybuf[oo][t] + ybuf[oo][256 + t], 0.f);
  }
  __syncthreads();

  const float GC = 0.63661977236758138f;
  const float GE = GC * 0.13533528323661270f;
  const float GD = GC * 0.018315638888734179f;

  if (t < KP2) {
    int h = 0, w2 = 0;
    if (t < HW) { h = t / 14; w2 = t - h * 14; }
#pragma unroll
    for (int oo = 0; oo < 4; ++oo) {
      float v = 0.f;
      if (t < HW) {
        const float* yb = &ybuf[oo][h * 16 + w2];
        v = GD * (yb[0] + yb[2] + yb[32] + yb[34])
          + GE * (yb[1] + yb[16] + yb[18] + yb[33])
          + GC * yb[17];
      }
      const int row = b * NC + og * 4 + oo;
      __hip_bfloat16 bv = __float2bfloat16(v);
      xf[row * KP2 + t] = bv;
      const int ir = (t < HW) ? ((t == 0) ? 0 : (HW - t)) : t;   // reversed index
      xfr[row * KP2 + ir] = bv;
    }
  }
}

// ---- Stage 2: circular correlation via MFMA; a-fold 4:1; bf16 W[b][a1][c*196+p] ----
// grid (8, 64) = (b, c-pair); 256 threads = 4 waves. flat_id%8==b -> XCD locality.
__global__ __launch_bounds__(256, 2) void k_cooc(const __hip_bfloat16* __restrict__ xf,
                                                 const __hip_bfloat16* __restrict__ xfr,
                                                 u32* __restrict__ W) {
  const int b     = blockIdx.x;
  const int cpair = blockIdx.y;   // 0..63
  const int t     = threadIdx.x;

  __shared__ __align__(16) u16 Abuf[NC * KP2];   // 59392 B
  __shared__ __align__(16) u16 ext[8 * CL];      // 6912 B (rebuilt per c)
  __shared__ __align__(16) u16 Obuf[32 * 200];   // 12800 B   total 79104 B

  { // stage reversed-A rows (all 128 rows of batch b), flat b128 copy
    const uint4* src = (const uint4*)(xfr + (size_t)b * NC * KP2);
    uint4* dst = (uint4*)Abuf;
    for (int j = t; j < NC * KP2 / 8; j += 256) dst[j] = src[j];
  }
  __syncthreads();

  const int lane = t & 63;
  const int wv   = t >> 6;        // p-tiles {wv, wv+4, wv+8} (+12 for wave 0)
  const int n    = lane & 15;
  const int quad = lane >> 4;
  const int S    = n & 7;
  const int extoff = S * CL + (n & 8) + quad * 8;
  const int arow   = n * KP2 + quad * 8;

  for (int c2 = 0; c2 < 2; ++c2) {
    const int c = cpair * 2 + c2;

    { // 8 shift-copies of forward row c: ext[S][m] = row_c[(m+S) mod 196]
      const u16* xfu = (const u16*)xf + (b * NC + c) * KP2;
      for (int j = t; j < 8 * CL; j += 256) {
        const int Sh = j / CL;
        const int m = j - Sh * CL;
        int idx = m + Sh;
        if (idx >= 2 * HW) idx -= 2 * HW; else if (idx >= HW) idx -= HW;
        ext[j] = xfu[idx];
      }
    }
    __syncthreads();

    floatx4 acc[8][4];
#pragma unroll
    for (int at = 0; at < 8; ++at)
#pragma unroll
      for (int j = 0; j < 4; ++j) acc[at][j] = (floatx4){0.f, 0.f, 0.f, 0.f};

    for (int kb = 0; kb < 7; ++kb) {
      const int i0 = kb * 32;
      bf16x8 af[8];
#pragma unroll
      for (int at = 0; at < 8; ++at)
        af[at] = *((const bf16x8*)&Abuf[(at * 16) * KP2 + arow + i0]);

#define DO_PT(JC)                                                                \
      {                                                                          \
        const int p0 = (wv + 4 * (JC)) * 16;                                     \
        const bf16x8 bv = *((const bf16x8*)&ext[extoff + p0 + i0]);              \
        _Pragma("unroll")                                                        \
        for (int at = 0; at < 8; ++at)                                           \
          acc[at][JC] = __builtin_amdgcn_mfma_f32_16x16x32_bf16(af[at], bv,      \
                                                                acc[at][JC], 0, 0, 0); \
      }
      DO_PT(0)
      DO_PT(1)
      DO_PT(2)
      if (wv == 0) { DO_PT(3) }
#undef DO_PT
    }

    // epilogue: in-register 4:1 a-fold, bf16 round, stage in Obuf[a1][p]
#define EPI(JC)                                                                  \
    {                                                                            \
      const int p = (wv + 4 * (JC)) * 16 + n;                                    \
      if (p < HW) {                                                              \
        _Pragma("unroll")                                                        \
        for (int a0t = 0; a0t < 2; ++a0t) {                                      \
          _Pragma("unroll")                                                      \
          for (int rr = 0; rr < 4; ++rr) {                                       \
            float v = fmaxf(fmaxf(acc[a0t][JC][rr], acc[a0t + 2][JC][rr]),       \
                            fmaxf(acc[a0t + 4][JC][rr], acc[a0t + 6][JC][rr]));  \
            const int a1 = a0t * 16 + quad * 4 + rr;                             \
            union { __hip_bfloat16 h; u16 u; } cv;                               \
            cv.h = __float2bfloat16(v);                                          \
            Obuf[a1 * 200 + p] = cv.u;                                           \
          }                                                                      \
        }                                                                        \
      }                                                                          \
    }
    EPI(0)
    EPI(1)
    EPI(2)
    if (wv == 0) { EPI(3) }
#undef EPI
    __syncthreads();

    { // coalesced store: 32 rows x 98 u32 into W[b][a1][c*98 + col]
      const u32* O32 = (const u32*)Obuf;
      u32* Wb = W + ((size_t)b * 32) * WROW + c * 98;
      for (int j = t; j < 32 * 98; j += 256) {
        const int row = (int)(((unsigned)j * 10700u) >> 20);   // j / 98, exact for j<43690
        const int col = j - row * 98;
        Wb[row * WROW + col] = O32[row * 100 + col];
      }
    }
    __syncthreads();   // Obuf/ext safe to rewrite
  }
}

// ---- Stage 3: per-slot max over 49 contributors (coalesced) + sqrt + batch sum ----
// thread handles 2 consecutive r via u32 (bf16 pair) reads; 256 blocks x 256.
__global__ __launch_bounds__(256) void k_max(const u32* __restrict__ W,
                                             float* __restrict__ out,
                                             float* __restrict__ sums) {
  const int gid = blockIdx.x * 256 + threadIdx.x;   // 0..65535
  const int b  = gid >> 13;
  const int r0 = (gid & 8191) << 1;
  const u32* Wb = W + (size_t)b * 32 * WROW;

  float m0 = 0.f, m1 = 0.f;
#pragma unroll 4
  for (int a1 = 0; a1 < 32; ++a1) {
    const int s = (r0 - ((a1 * 8704) & 16383)) & 16383;   // even
    const u32 v = Wb[a1 * WROW + (s >> 1)];
    m0 = fmaxf(m0, __uint_as_float((v & 0xffffu) << 16));
    m1 = fmaxf(m1, __uint_as_float(v & 0xffff0000u));
    if (s < 8704) {   // second contributor s+16384 < 25088
      const u32 v2 = Wb[a1 * WROW + ((s + 16384) >> 1)];
      m0 = fmaxf(m0, __uint_as_float((v2 & 0xffffu) << 16));
      m1 = fmaxf(m1, __uint_as_float(v2 & 0xffff0000u));
    }
  }
  const int o = b * 16384 + r0;
  out[o]     = sqrtf(m0);
  out[o + 1] = sqrtf(m1);

  float s2 = m0 + m1;   // per-batch sum of c_ij^2 (pre-normalize)
#pragma unroll
  for (int off = 32; off > 0; off >>= 1) s2 += __shfl_down(s2, off, 64);
  __shared__ float part[4];
  if ((threadIdx.x & 63) == 0) part[threadIdx.x >> 6] = s2;
  __syncthreads();
  if (threadIdx.x == 0)
    atomicAdd(&sums[b], part[0] + part[1] + part[2] + part[3]);
}

// ---- Stage 4: normalize ----
__global__ __launch_bounds__(256) void k_norm(const float* __restrict__ sums,
                                              float* __restrict__ out) {
  const int gid = blockIdx.x * 256 + threadIdx.x;
  const int b = gid >> 14;
  out[gid] = out[gid] / (sums[b] + 1e-11f);
}

extern "C" void kernel_launch(void* const* d_in, const int* in_sizes, int n_in,
                              void* d_out, int out_size, void* d_ws, size_t ws_size,
                              hipStream_t stream) {
  const float* x  = (const float*)d_in[0];   // (8,512,16,16) fp32
  const float* wc = (const float*)d_in[1];   // (128,512) fp32

  char* ws = (char*)d_ws;
  __hip_bfloat16* xf  = (__hip_bfloat16*)ws;                       // 475136 B
  __hip_bfloat16* xfr = (__hip_bfloat16*)(ws + 475136);            // 475136 B
  u32* W      = (u32*)(ws + 950272);                               // 12845056 B
  float* sums = (float*)(ws + 950272 + 12845056);                  // 32 B

  hipMemsetAsync(sums, 0, NB * sizeof(float), stream);
  k_stage1<<<dim3(NB, 32), 512, 0, stream>>>(x, wc, xf, xfr);
  k_cooc<<<dim3(NB, 64), 256, 0, stream>>>(xf, xfr, W);
  k_max<<<256, 256, 0, stream>>>(W, (float*)d_out, sums);
  k_norm<<<(NB * 16384) / 256, 256, 0, stream>>>(sums, (float*)d_out);
}